// Round 2
// baseline (558.445 us; speedup 1.0000x reference)
//
#include <hip/hip_runtime.h>
#include <math.h>

// FeedForwardQuantum: closed-form quantum layer + fused fp32 FFN.
//
// Quantum layer closed form (Heisenberg conjugation through the CNOT ring):
//   c_w     = cos(x[n,w] + rx[w])            (RX angles add on the same wire)
//   q[n,0]  = c_1*c_2*...*c_9
//   q[n,w]  = c_0*c_1*...*c_w   (w = 1..9)
// Then: out = relu(q @ w1^T + b1) @ w2^T + b2.
// Dominant cost: M=16384, K=2048, N=512 fp32 GEMM = 34.4 GFLOP (vector-ALU
// bound on CDNA4: no fp32 MFMA; roofline 219 us at 157.3 TF).

constexpr int EDIM = 512;   // embed dim (x row stride, output cols)
constexpr int FDIM = 2048;  // ffn dim (K of the big GEMM)
constexpr int NQ   = 10;    // qubits
constexpr int BM   = 64;    // tokens per block
constexpr int BK   = 16;    // K chunk
constexpr int NTHREADS = 512;

__global__ __launch_bounds__(NTHREADS, 2) void ffq_fused(
    const float* __restrict__ x,
    const float* __restrict__ rx,
    const float* __restrict__ w1,
    const float* __restrict__ b1,
    const float* __restrict__ w2,
    const float* __restrict__ b2,
    float* __restrict__ out,
    int M)
{
    __shared__ float q_lds[BM][NQ];        // 2.5 KB
    __shared__ float h_lds[BK][BM];        // 4 KB   (k-major: broadcast reads)
    __shared__ float w2_lds[BK][EDIM];     // 32 KB  (k-major: b128 consecutive reads)

    const int tid = threadIdx.x;
    const int m0  = blockIdx.x * BM;
    if (m0 >= M) return;   // defensive; M=16384 divides evenly in practice

    // ---- Phase 1: quantum layer (closed form), one thread per token ----
    if (tid < BM) {
        const float* xr = x + (size_t)(m0 + tid) * EDIM;
        float c[NQ];
        #pragma unroll
        for (int w = 0; w < NQ; ++w) c[w] = cosf(xr[w] + rx[w]);
        float p0 = c[1];
        #pragma unroll
        for (int w = 2; w < NQ; ++w) p0 *= c[w];
        q_lds[tid][0] = p0;                 // <Z_0> = prod_{1..9} cos
        float p = c[0];
        #pragma unroll
        for (int w = 1; w < NQ; ++w) { p *= c[w]; q_lds[tid][w] = p; }  // prefix products
    }
    __syncthreads();

    // ---- h-producer mapping: thread -> (kk_h, mh) and (kk_h, mh+32) ----
    const int kk_h = tid >> 5;   // 0..15
    const int mh   = tid & 31;   // 0..31
    float qA[NQ], qB[NQ];
    #pragma unroll
    for (int q = 0; q < NQ; ++q) { qA[q] = q_lds[mh][q]; qB[q] = q_lds[mh + 32][q]; }

    // ---- GEMM consumer mapping: micro-tile 16(m) x 4(e) per thread ----
    const int ec = tid & 127;    // e block: floats [4*ec .. 4*ec+3]
    const int mr = tid >> 7;     // m block: rows [16*mr .. 16*mr+15]

    float acc[16][4];
    #pragma unroll
    for (int mi = 0; mi < 16; ++mi) {
        #pragma unroll
        for (int v = 0; v < 4; ++v) acc[mi][v] = 0.f;
    }

    // thread t stages w2 row e=t (the LDS-transpose)
    const float* w2row = w2 + (size_t)tid * FDIM;

    // ---- register prefetch of chunk 0 ----
    float4 s0, s1, s2, s3;
    float hA, hB;
    {
        s0 = *(const float4*)(w2row + 0);
        s1 = *(const float4*)(w2row + 4);
        s2 = *(const float4*)(w2row + 8);
        s3 = *(const float4*)(w2row + 12);
        const float* w1r = w1 + (size_t)kk_h * NQ;
        const float bb = b1[kk_h];
        hA = bb; hB = bb;
        #pragma unroll
        for (int q = 0; q < NQ; ++q) {
            const float wq = w1r[q];
            hA = fmaf(qA[q], wq, hA);
            hB = fmaf(qB[q], wq, hB);
        }
    }

    for (int k0 = 0; k0 < FDIM; k0 += BK) {
        // ---- commit staged chunk to LDS (all patterns conflict-free/2-way) ----
        w2_lds[ 0][tid] = s0.x;  w2_lds[ 1][tid] = s0.y;
        w2_lds[ 2][tid] = s0.z;  w2_lds[ 3][tid] = s0.w;
        w2_lds[ 4][tid] = s1.x;  w2_lds[ 5][tid] = s1.y;
        w2_lds[ 6][tid] = s1.z;  w2_lds[ 7][tid] = s1.w;
        w2_lds[ 8][tid] = s2.x;  w2_lds[ 9][tid] = s2.y;
        w2_lds[10][tid] = s2.z;  w2_lds[11][tid] = s2.w;
        w2_lds[12][tid] = s3.x;  w2_lds[13][tid] = s3.y;
        w2_lds[14][tid] = s3.z;  w2_lds[15][tid] = s3.w;
        h_lds[kk_h][mh]      = fmaxf(hA, 0.f);
        h_lds[kk_h][mh + 32] = fmaxf(hB, 0.f);
        __syncthreads();

        // ---- prefetch next chunk into registers (hidden behind FMA loop) ----
        const int kn = k0 + BK;
        if (kn < FDIM) {
            s0 = *(const float4*)(w2row + kn);
            s1 = *(const float4*)(w2row + kn + 4);
            s2 = *(const float4*)(w2row + kn + 8);
            s3 = *(const float4*)(w2row + kn + 12);
            const float* w1r = w1 + (size_t)(kn + kk_h) * NQ;
            const float bb = b1[kn + kk_h];
            hA = bb; hB = bb;
            #pragma unroll
            for (int q = 0; q < NQ; ++q) {
                const float wq = w1r[q];
                hA = fmaf(qA[q], wq, hA);
                hB = fmaf(qB[q], wq, hB);
            }
        }

        // ---- FMA core: 16 kk x 64 FMA per thread ----
        #pragma unroll
        for (int kk = 0; kk < BK; ++kk) {
            const float4 wv = *(const float4*)&w2_lds[kk][ec << 2];
            const float4* hp = (const float4*)&h_lds[kk][mr << 4];
            float hv[16];
            *(float4*)&hv[ 0] = hp[0];
            *(float4*)&hv[ 4] = hp[1];
            *(float4*)&hv[ 8] = hp[2];
            *(float4*)&hv[12] = hp[3];
            #pragma unroll
            for (int mi = 0; mi < 16; ++mi) {
                const float h = hv[mi];
                acc[mi][0] = fmaf(h, wv.x, acc[mi][0]);
                acc[mi][1] = fmaf(h, wv.y, acc[mi][1]);
                acc[mi][2] = fmaf(h, wv.z, acc[mi][2]);
                acc[mi][3] = fmaf(h, wv.w, acc[mi][3]);
            }
        }
        __syncthreads();
    }

    // ---- epilogue: + b2, coalesced float4 stores ----
    const float4 bv = *(const float4*)(b2 + (ec << 2));
    #pragma unroll
    for (int mi = 0; mi < 16; ++mi) {
        const int m = m0 + (mr << 4) + mi;
        float4 o;
        o.x = acc[mi][0] + bv.x;
        o.y = acc[mi][1] + bv.y;
        o.z = acc[mi][2] + bv.z;
        o.w = acc[mi][3] + bv.w;
        *(float4*)(out + (size_t)m * EDIM + (ec << 2)) = o;
    }
}

extern "C" void kernel_launch(void* const* d_in, const int* in_sizes, int n_in,
                              void* d_out, int out_size, void* d_ws, size_t ws_size,
                              hipStream_t stream) {
    const float* x  = (const float*)d_in[0];
    const float* rx = (const float*)d_in[1];
    const float* w1 = (const float*)d_in[2];
    const float* b1 = (const float*)d_in[3];
    const float* w2 = (const float*)d_in[4];
    const float* b2 = (const float*)d_in[5];
    float* out = (float*)d_out;

    const int M = in_sizes[0] / EDIM;   // 16384 tokens
    dim3 grid((M + BM - 1) / BM), block(NTHREADS);
    hipLaunchKernelGGL(ffq_fused, grid, block, 0, stream,
                       x, rx, w1, b1, w2, b2, out, M);
}

// Round 3
// 186.102 us; speedup vs baseline: 3.0007x; 3.0007x over previous
//
#include <hip/hip_runtime.h>
#include <math.h>

// FeedForwardQuantum — bf16-MFMA fused pipeline.
//
// Quantum layer closed form (verified vs state-vector algebra):
//   c_w = cos(x[n,w] + rx[w]);  q[n,0] = prod_{1..9} c;  q[n,w] = prod_{0..w} c
// h = relu(q @ w1^T + b1)  [GEMM1, K=10 padded to 32, MFMA]
// out = h @ w2^T + b2      [GEMM2, M=16384 K=2048 N=512, MFMA]
//
// prep kernel: w2 -> bf16 (d_ws), w1 -> zero-padded [2048][32] bf16 (d_ws).
// Main kernel: per 128x128 C-tile, K-loop of 32: GEMM1(i+1) in regs ->
// LDS round-trip (swizzled) -> GEMM2(i) with B-frags loaded straight from
// L2-resident bf16 w2. Single LDS buffer, register prefetch one chunk ahead.

typedef __attribute__((ext_vector_type(8))) short short8;
typedef __attribute__((ext_vector_type(4))) float fx4;

constexpr int EDIM = 512;
constexpr int FDIM = 2048;
constexpr int NQ   = 10;
constexpr int BM   = 128;
constexpr int BN   = 128;
constexpr int BK   = 32;
constexpr int NT   = 256;           // 4 waves
constexpr int NCH  = FDIM / BK;     // 64 K-chunks

__device__ __forceinline__ ushort f2bf(float f) {   // f32 -> bf16, RNE
    union { float f; unsigned u; } v; v.f = f;
    unsigned u = v.u + 0x7FFFu + ((v.u >> 16) & 1u);
    return (ushort)(u >> 16);
}

// ---- prep: w2 f32 -> bf16; w1 -> [FDIM][32] bf16 zero-padded ----
__global__ void prep(const float* __restrict__ w1, const float* __restrict__ w2,
                     ushort* __restrict__ w2b, ushort* __restrict__ w1p) {
    int gid = blockIdx.x * blockDim.x + threadIdx.x;
    int np  = gridDim.x * blockDim.x;
    for (int i = gid; i < EDIM * FDIM / 4; i += np) {
        float4 v = ((const float4*)w2)[i];
        ushort4 o; o.x = f2bf(v.x); o.y = f2bf(v.y); o.z = f2bf(v.z); o.w = f2bf(v.w);
        ((ushort4*)w2b)[i] = o;
    }
    for (int i = gid; i < FDIM * 32; i += np) {
        int r = i >> 5, c = i & 31;
        w1p[i] = (c < NQ) ? f2bf(w1[r * NQ + c]) : (ushort)0;
    }
}

__global__ __launch_bounds__(NT, 2) void ffq(
    const float* __restrict__ x,
    const float* __restrict__ rx,
    const float* __restrict__ b1,
    const float* __restrict__ b2,
    const ushort* __restrict__ w2b,   // [EDIM][FDIM] bf16
    const ushort* __restrict__ w1p,   // [FDIM][32] bf16, cols 10..31 = 0
    float* __restrict__ out)
{
    __shared__ ushort qs[BM * 32];    // q, K padded to 32 (cols 10..31 zero)
    __shared__ ushort As[BM * 32];    // h chunk, column-block-swizzled

    const int tid  = threadIdx.x;
    const int bm   = blockIdx.x & 127, bn = blockIdx.x >> 7;
    const int m0   = bm * BM, n0 = bn * BN;
    const int wave = tid >> 6, lane = tid & 63;
    const int quad = lane >> 4, l16 = lane & 15;
    const int wm   = wave >> 1, wn = wave & 1;

    // ---- preamble: closed-form quantum layer -> qs ----
    if (tid < BM) {
        const float* xr = x + (size_t)(m0 + tid) * EDIM;
        float c[NQ], q[NQ];
        #pragma unroll
        for (int w = 0; w < NQ; ++w) c[w] = cosf(xr[w] + rx[w]);
        float p0 = c[1];
        #pragma unroll
        for (int w = 2; w < NQ; ++w) p0 *= c[w];
        q[0] = p0;
        float p = c[0];
        #pragma unroll
        for (int w = 1; w < NQ; ++w) { p *= c[w]; q[w] = p; }
        ushort* row = &qs[tid * 32];
        #pragma unroll
        for (int w = 0; w < NQ; ++w) row[w] = f2bf(q[w]);
        #pragma unroll
        for (int w = NQ; w < 32; ++w) row[w] = 0;
    }
    __syncthreads();

    // persistent q A-frags for GEMM1 m-tiles gmt = wave*2 + {0,1}
    short8 qf[2];
    #pragma unroll
    for (int t = 0; t < 2; ++t) {
        int m = (wave * 2 + t) * 16 + l16;
        qf[t] = *(const short8*)&qs[m * 32 + quad * 8];
    }

    // ---- global frag bases ----
    // B-frag (GEMM2): w2b[(n0 + wn*64 + nt*16 + l16)*FDIM + k0 + quad*8]
    const ushort* bbase = w2b + (size_t)(n0 + wn * 64 + l16) * FDIM + quad * 8;
    // w1-frag (GEMM1): w1p[(k0 + s*16 + l16)*32 + quad*8]  (k1 = quad*8+j; q=0 for k1>=10)
    const ushort* w1base = w1p + (size_t)l16 * 32 + quad * 8;

    // A (h) LDS addressing, swizzle: column block (0..3) ^= (row>>2)&3
    // write: row = (wave*2+t)*16 + quad*4 + r; col = s*16 + l16
    // (row>>2)&3 == quad for writes; == (l16>>2)&3 for reads
    const int aw_row0 = (wave * 2) * 16 + quad * 4;
    const int ar_row0 = wm * 64 + l16;
    const int ar_swz  = (l16 >> 2) & 3;

    fx4 acc[4][4];
    #pragma unroll
    for (int a = 0; a < 4; ++a)
        #pragma unroll
        for (int b = 0; b < 4; ++b) acc[a][b] = fx4{0.f, 0.f, 0.f, 0.f};

    ushort hp[16];   // pipelined GEMM1 output (4 tiles x 4 regs), bf16 bits

    // ---- GEMM1 for chunk 0 (latency exposed once) ----
    {
        short8 w1f[2]; float b1v[2];
        #pragma unroll
        for (int s = 0; s < 2; ++s) {
            w1f[s] = *(const short8*)&w1base[(size_t)(s * 16) * 32];
            b1v[s] = b1[s * 16 + l16];
        }
        #pragma unroll
        for (int t = 0; t < 2; ++t)
            #pragma unroll
            for (int s = 0; s < 2; ++s) {
                fx4 h = fx4{b1v[s], b1v[s], b1v[s], b1v[s]};
                h = __builtin_amdgcn_mfma_f32_16x16x32_bf16(qf[t], w1f[s], h, 0, 0, 0);
                #pragma unroll
                for (int r = 0; r < 4; ++r)
                    hp[(t * 2 + s) * 4 + r] = f2bf(fmaxf(h[r], 0.f));
            }
    }

    // ---- B-frags for chunk 0 ----
    short8 bf[4];
    #pragma unroll
    for (int nt = 0; nt < 4; ++nt)
        bf[nt] = *(const short8*)&bbase[(size_t)nt * 16 * FDIM];

    for (int i = 0; i < NCH; ++i) {
        const int k0 = i * BK;

        // ---- write phase: commit h chunk i (swizzled) ----
        #pragma unroll
        for (int t = 0; t < 2; ++t)
            #pragma unroll
            for (int s = 0; s < 2; ++s)
                #pragma unroll
                for (int r = 0; r < 4; ++r) {
                    int row = aw_row0 + t * 16 + r;
                    int colb = (s * 2 + (l16 >> 3)) ^ quad;   // swizzled col block
                    As[row * 32 + colb * 8 + (l16 & 7)] = hp[(t * 2 + s) * 4 + r];
                }
        __syncthreads();

        // ---- prefetch chunk i+1 (globals in flight across the MFMA body) ----
        const int kn = k0 + BK;
        short8 bfn[4], w1fn[2]; float b1vn[2];
        if (i + 1 < NCH) {
            #pragma unroll
            for (int nt = 0; nt < 4; ++nt)
                bfn[nt] = *(const short8*)&bbase[(size_t)nt * 16 * FDIM + kn];
            #pragma unroll
            for (int s = 0; s < 2; ++s) {
                w1fn[s] = *(const short8*)&w1base[(size_t)(kn + s * 16) * 32];
                b1vn[s] = b1[kn + s * 16 + l16];
            }
        }

        // ---- GEMM2 chunk i ----
        short8 af[4];
        #pragma unroll
        for (int mt = 0; mt < 4; ++mt) {
            int row = ar_row0 + mt * 16;
            af[mt] = *(const short8*)&As[row * 32 + (quad ^ ar_swz) * 8];
        }
        #pragma unroll
        for (int mt = 0; mt < 4; ++mt)
            #pragma unroll
            for (int nt = 0; nt < 4; ++nt)
                acc[mt][nt] = __builtin_amdgcn_mfma_f32_16x16x32_bf16(
                    af[mt], bf[nt], acc[mt][nt], 0, 0, 0);

        // ---- GEMM1 chunk i+1 ----
        if (i + 1 < NCH) {
            #pragma unroll
            for (int t = 0; t < 2; ++t)
                #pragma unroll
                for (int s = 0; s < 2; ++s) {
                    fx4 h = fx4{b1vn[s], b1vn[s], b1vn[s], b1vn[s]};
                    h = __builtin_amdgcn_mfma_f32_16x16x32_bf16(qf[t], w1fn[s], h, 0, 0, 0);
                    #pragma unroll
                    for (int r = 0; r < 4; ++r)
                        hp[(t * 2 + s) * 4 + r] = f2bf(fmaxf(h[r], 0.f));
                }
            #pragma unroll
            for (int nt = 0; nt < 4; ++nt) bf[nt] = bfn[nt];
        }
        __syncthreads();
    }

    // ---- epilogue: + b2, C-layout stores (col=lane&15, row=quad*4+r) ----
    float bb[4];
    #pragma unroll
    for (int nt = 0; nt < 4; ++nt) bb[nt] = b2[n0 + wn * 64 + nt * 16 + l16];
    #pragma unroll
    for (int mt = 0; mt < 4; ++mt) {
        const int mbase = m0 + wm * 64 + mt * 16 + quad * 4;
        #pragma unroll
        for (int nt = 0; nt < 4; ++nt) {
            const int n = n0 + wn * 64 + nt * 16 + l16;
            #pragma unroll
            for (int r = 0; r < 4; ++r)
                out[(size_t)(mbase + r) * EDIM + n] = acc[mt][nt][r] + bb[nt];
        }
    }
}

extern "C" void kernel_launch(void* const* d_in, const int* in_sizes, int n_in,
                              void* d_out, int out_size, void* d_ws, size_t ws_size,
                              hipStream_t stream) {
    const float* x  = (const float*)d_in[0];
    const float* rx = (const float*)d_in[1];
    const float* w1 = (const float*)d_in[2];
    const float* b1 = (const float*)d_in[3];
    const float* w2 = (const float*)d_in[4];
    const float* b2 = (const float*)d_in[5];
    float* out = (float*)d_out;

    // ws layout: [0, 2 MiB) w2 bf16; [2 MiB, 2 MiB+128 KiB) w1 padded bf16
    ushort* w2b = (ushort*)d_ws;
    ushort* w1p = (ushort*)((char*)d_ws + (size_t)EDIM * FDIM * 2);

    hipLaunchKernelGGL(prep, dim3(512), dim3(256), 0, stream, w1, w2, w2b, w1p);

    const int M = in_sizes[0] / EDIM;                 // 16384
    dim3 grid((M / BM) * (EDIM / BN)), block(NT);     // 512 blocks, 256 thr
    hipLaunchKernelGGL(ffq, grid, block, 0, stream,
                       x, rx, b1, b2, w2b, w1p, out);
}